// Round 9
// baseline (425.273 us; speedup 1.0000x reference)
//
#include <hip/hip_runtime.h>
#include <hip/hip_cooperative_groups.h>
#include <hip/hip_bf16.h>
#include <hip/hip_fp16.h>

// GCN round 9: single cooperative mega-kernel. 256 blocks x 1024 threads
// (1 block/CU, 16 waves/CU). Phases separated by grid.sync():
//  P0 weight-transpose + LDS hist (stays resident) + flush to total
//  P1 encoder MFMA GEMM + per-block local scan
//  P2 256-wide block-offset scan -> rs/cur
//  P3 claim (global atomicAdd per nonzero hist entry) + scatter + conv1 GEMM
//  P4.. agg / gemm alternation, decoder GEMM.
// CSR payload packed 4B (src:14b | fp16 weight). h/hw fp16, fp32 accum.

#define NNODES 10000
#define NEDGES 640000
#define HDIM   128
#define CDIM   64
#define NBLK   256
#define NTHR   1024
#define ECHUNK (NEDGES / NBLK)   // 2500 edges per block
#define NPB    40                // nodes per block for scan (250 blocks used)

typedef _Float16 half8 __attribute__((ext_vector_type(8)));
typedef float    f32x4 __attribute__((ext_vector_type(4)));

struct GcnParams {
    const float* x;
    const int*   src;
    const int*   dst;
    const float* ew;
    const float* enc_W; const float* enc_b;
    const float* conv_W; const float* conv_b;
    const float* dec_W; const float* dec_b;
    float* out;
    _Float16* h;
    _Float16* hw;
    _Float16* wt;
    unsigned int* csr;
    int* total; int* rs; int* cur; int* bsum;
};

// ---- one 16-row GEMM tile, executed by a 256-thread subgroup ----
template<int NCOLS, bool BIAS, bool TANH, bool OUTF32, bool AF32>
__device__ __forceinline__ void gemm_tile(int tile, int tid, const void* Av,
                                          const _Float16* Wt, const float* bias,
                                          void* outv)
{
    constexpr int TPW = NCOLS / 64;
    const int wave = tid >> 6;          // 0..3
    const int lane = tid & 63;
    const int base = tile * 16;
    const int m = lane & 15, kg = lane >> 4;
    const int row = base + m;

    f32x4 acc[TPW];
    #pragma unroll
    for (int q = 0; q < TPW; ++q) acc[q] = (f32x4){0.f, 0.f, 0.f, 0.f};

    #pragma unroll
    for (int ks = 0; ks < 4; ++ks) {
        half8 a;
        if (AF32) {
            const float* ap = (const float*)Av + (size_t)row * 128 + kg * 8 + ks * 32;
            float4 u0 = *(const float4*)ap;
            float4 u1 = *(const float4*)(ap + 4);
            a[0] = (_Float16)u0.x; a[1] = (_Float16)u0.y;
            a[2] = (_Float16)u0.z; a[3] = (_Float16)u0.w;
            a[4] = (_Float16)u1.x; a[5] = (_Float16)u1.y;
            a[6] = (_Float16)u1.z; a[7] = (_Float16)u1.w;
        } else {
            a = *(const half8*)((const _Float16*)Av + (size_t)row * 128 + kg * 8 + ks * 32);
        }
        #pragma unroll
        for (int q = 0; q < TPW; ++q) {
            const int nt = wave + q * 4;
            half8 bb = *(const half8*)(Wt + (size_t)(nt * 16 + m) * 128 + ks * 32 + kg * 8);
            acc[q] = __builtin_amdgcn_mfma_f32_16x16x32_f16(a, bb, acc[q], 0, 0, 0);
        }
    }

    #pragma unroll
    for (int q = 0; q < TPW; ++q) {
        const int col = (wave + q * 4) * 16 + m;
        float bv = BIAS ? bias[col] : 0.f;
        #pragma unroll
        for (int r = 0; r < 4; ++r) {
            int orow = base + kg * 4 + r;
            float v = acc[q][r] + bv;
            if (TANH) v = tanhf(v);
            if (OUTF32) ((float*)outv)[(size_t)orow * NCOLS + col] = v;
            else        ((_Float16*)outv)[(size_t)orow * NCOLS + col] = (_Float16)v;
        }
    }
}

#define AGG_ACC(pw, vw)                                                  \
    do {                                                                 \
        __half wh; *(unsigned short*)&wh = (unsigned short)((pw) >> 16); \
        float w  = __half2float(wh);                                     \
        float2 f = __half22float2(*(const __half2*)&(vw));               \
        ax += w * f.x;                                                   \
        ay += w * f.y;                                                   \
    } while (0)

// ---- one node's aggregation, executed by a wave (R6 16/4/1 structure) ----
__device__ __forceinline__ void agg_node(int wid, int lane,
    const unsigned int* __restrict__ hwu, const int* __restrict__ rs,
    const unsigned int* __restrict__ csr, const float* __restrict__ bias,
    unsigned int* __restrict__ hout)
{
    const int e0 = rs[wid];
    const int e1 = rs[wid + 1];

    float ax = 0.f, ay = 0.f;
    int e = e0;
    for (; e + 16 <= e1; e += 16) {
        unsigned int p[16], v[16];
        #pragma unroll
        for (int j = 0; j < 16; ++j) p[j] = csr[e + j];          // uniform -> s_load
        #pragma unroll
        for (int j = 0; j < 16; ++j) v[j] = hwu[((p[j] & 0x3FFFu) << 6) + lane];
        #pragma unroll
        for (int j = 0; j < 16; ++j) AGG_ACC(p[j], v[j]);
    }
    for (; e + 4 <= e1; e += 4) {
        unsigned int p[4], v[4];
        #pragma unroll
        for (int j = 0; j < 4; ++j) p[j] = csr[e + j];
        #pragma unroll
        for (int j = 0; j < 4; ++j) v[j] = hwu[((p[j] & 0x3FFFu) << 6) + lane];
        #pragma unroll
        for (int j = 0; j < 4; ++j) AGG_ACC(p[j], v[j]);
    }
    for (; e < e1; ++e) {
        unsigned int p = csr[e];
        unsigned int u = hwu[((p & 0x3FFFu) << 6) + lane];
        AGG_ACC(p, u);
    }

    float2 bv = ((const float2*)bias)[lane];
    __half2 o = __floats2half2_rn(tanhf(ax + bv.x), tanhf(ay + bv.y));
    hout[((size_t)wid << 6) + lane] = *(unsigned int*)&o;
}

__global__ __launch_bounds__(NTHR, 4) void gcn_mega(GcnParams P)
{
    cooperative_groups::grid_group grid = cooperative_groups::this_grid();
    __shared__ int hist[NNODES];   // 40KB, resident P0 -> P3
    __shared__ int sc2[NPB];
    __shared__ int sb[NBLK];

    const int b = blockIdx.x, t = threadIdx.x;

    // ---------- P0: weight transpose + LDS hist + flush (total pre-zeroed) ----------
    for (int idx = b * NTHR + t; idx < 5 * 16384 - 8192; idx += NBLK * NTHR) {
        if (idx < 65536) {
            int wsel = idx >> 14, off = idx & 16383;
            int n = off >> 7, k = off & 127;
            const float* W = (wsel == 0) ? P.enc_W : P.conv_W + (wsel - 1) * 16384;
            P.wt[idx] = (_Float16)W[k * 128 + n];
        } else {
            int off = idx - 65536;
            int n = off >> 7, k = off & 127;
            P.wt[idx] = (_Float16)P.dec_W[k * 64 + n];
        }
    }
    for (int i = t; i < NNODES; i += NTHR) hist[i] = 0;
    __syncthreads();
    {
        const int e0 = b * ECHUNK;
        for (int e = e0 + t; e < e0 + ECHUNK; e += NTHR)
            atomicAdd(&hist[P.dst[e]], 1);
    }
    __syncthreads();
    for (int i = t; i < NNODES; i += NTHR) {
        int c = hist[i];
        if (c) atomicAdd(&P.total[i], c);
    }
    grid.sync();

    // ---------- P1: encoder GEMM (x fp32 -> h fp16) + per-block local scan ----------
    for (int g = b * 4 + (t >> 8); g < NNODES / 16; g += NBLK * 4)
        gemm_tile<128, true, true, false, true>(g, t & 255, P.x, P.wt, P.enc_b, P.h);
    if (t < NPB) { int i = b * NPB + t; sc2[t] = (i < NNODES) ? P.total[i] : 0; }
    __syncthreads();
    if (t == 0) {
        int run = 0;
        #pragma unroll
        for (int j = 0; j < NPB; ++j) { int c = sc2[j]; sc2[j] = run; run += c; }
        P.bsum[b] = run;
    }
    grid.sync();

    // ---------- P2: 256-wide block-offset scan -> rs, cur ----------
    if (t < NBLK) sb[t] = P.bsum[t];
    __syncthreads();
    for (int off = 1; off < NBLK; off <<= 1) {
        int v = (t >= off && t < NBLK) ? sb[t - off] : 0;
        __syncthreads();
        if (t < NBLK) sb[t] += v;
        __syncthreads();
    }
    {
        int excl = sb[b] - P.bsum[b];        // exclusive offset for this block
        if (t < NPB) {
            int i = b * NPB + t;
            if (i < NNODES) { int v = excl + sc2[t]; P.rs[i] = v; P.cur[i] = v; }
        }
        if (b == 0 && t == 0) P.rs[NNODES] = NEDGES;
    }
    grid.sync();

    // ---------- P3: claim + scatter (LDS hist resident) + conv1 GEMM ----------
    for (int i = t; i < NNODES; i += NTHR) {
        int c = hist[i];
        if (c) hist[i] = atomicAdd(&P.cur[i], c);
    }
    __syncthreads();
    {
        const int e0 = b * ECHUNK;
        for (int e = e0 + t; e < e0 + ECHUNK; e += NTHR) {
            int d = P.dst[e];
            int p = atomicAdd(&hist[d], 1);
            unsigned int pk = (unsigned int)P.src[e]
                            | ((unsigned int)__half_as_ushort(__float2half_rn(P.ew[e])) << 16);
            P.csr[p] = pk;
        }
    }
    for (int g = b * 4 + (t >> 8); g < NNODES / 16; g += NBLK * 4)
        gemm_tile<128, false, false, false, false>(g, t & 255, P.h, P.wt + 16384, nullptr, P.hw);
    grid.sync();

    // ---------- layers: agg / gemm alternation ----------
    const int wv   = __builtin_amdgcn_readfirstlane(t >> 6);
    const int lane = t & 63;
    for (int L = 0; L < 3; ++L) {
        for (int wid = b * 16 + wv; wid < NNODES; wid += NBLK * 16)
            agg_node(wid, lane, (const unsigned int*)P.hw, P.rs, P.csr,
                     P.conv_b + L * 128, (unsigned int*)P.h);
        grid.sync();
        if (L < 2) {
            for (int g = b * 4 + (t >> 8); g < NNODES / 16; g += NBLK * 4)
                gemm_tile<128, false, false, false, false>(g, t & 255, P.h,
                    P.wt + (2 + L) * 16384, nullptr, P.hw);
            grid.sync();
        }
    }

    // ---------- decoder ----------
    for (int g = b * 4 + (t >> 8); g < NNODES / 16; g += NBLK * 4)
        gemm_tile<64, true, false, true, false>(g, t & 255, P.h, P.wt + 4 * 16384, P.dec_b, P.out);
}

// ---------------- launch ----------------
extern "C" void kernel_launch(void* const* d_in, const int* in_sizes, int n_in,
                              void* d_out, int out_size, void* d_ws, size_t ws_size,
                              hipStream_t stream)
{
    const float* x      = (const float*)d_in[0];
    const int*   ei     = (const int*)  d_in[1];
    const float* ew     = (const float*)d_in[2];
    const float* enc_W  = (const float*)d_in[3];
    const float* enc_b  = (const float*)d_in[4];
    const float* conv_W = (const float*)d_in[5];
    const float* conv_b = (const float*)d_in[6];
    const float* dec_W  = (const float*)d_in[7];
    const float* dec_b  = (const float*)d_in[8];

    const int N = NNODES, E = NEDGES, H = HDIM;

    _Float16*     h      = (_Float16*)d_ws;                     // [N,128]  2.56MB
    _Float16*     hw     = h + (size_t)N * H;                   // [N,128]  2.56MB
    _Float16*     wt     = hw + (size_t)N * H;                  // 73728    144KB
    unsigned int* csr    = (unsigned int*)(wt + 5 * 16384);     // [E]      2.56MB
    int*          total  = (int*)(csr + E);                     // [N]
    int*          rs     = total + N;                           // [N+1]
    int*          cur    = rs + (N + 1);                        // [N]
    int*          bsum   = cur + N;                             // [NBLK]

    GcnParams P;
    P.x = x; P.src = ei; P.dst = ei + E; P.ew = ew;
    P.enc_W = enc_W; P.enc_b = enc_b;
    P.conv_W = conv_W; P.conv_b = conv_b;
    P.dec_W = dec_W; P.dec_b = dec_b;
    P.out = (float*)d_out;
    P.h = h; P.hw = hw; P.wt = wt; P.csr = csr;
    P.total = total; P.rs = rs; P.cur = cur; P.bsum = bsum;

    hipMemsetAsync(total, 0, N * sizeof(int), stream);

    void* args[] = { (void*)&P };
    hipLaunchCooperativeKernel(reinterpret_cast<const void*>(&gcn_mega),
                               dim3(NBLK), dim3(NTHR), args, 0, stream);
}

// Round 10
// 133.898 us; speedup vs baseline: 3.1761x; 3.1761x over previous
//
#include <hip/hip_runtime.h>
#include <hip/hip_bf16.h>
#include <hip/hip_fp16.h>

// GCN round 10: linearity reorder — agg = (sum w*h[src]) @ W. Fused per-layer
// kernel: wave-aggregate 16 nodes into padded LDS tile -> MFMA -> bias+tanh.
// CSR build identical to round 6 (best measured). 10 launches total.

#define NNODES 10000
#define NEDGES 640000
#define HDIM   128
#define CDIM   64
#define NLAYER 3
#define NB     200
#define CHUNK  (NEDGES / NB)

typedef _Float16 half8 __attribute__((ext_vector_type(8)));
typedef float    f32x4 __attribute__((ext_vector_type(4)));

// ---------------- prep: weights -> transposed fp16 [n][k]; zero total ----------------
__global__ __launch_bounds__(256) void prep_kernel(
    const float* __restrict__ enc_W,
    const float* __restrict__ conv_W,
    const float* __restrict__ dec_W,
    _Float16* __restrict__ wt_all,     // enc[16384] conv[3*16384] dec[8192]
    int* __restrict__ total)
{
    const int b = blockIdx.x, t = threadIdx.x;
    if (b == 5) {
        for (int i = t; i < NNODES; i += 256) total[i] = 0;
        return;
    }
    const float* W; _Float16* Wt; int NC, tot;
    if (b == 0)      { W = enc_W;                  Wt = wt_all;             NC = 128; tot = 16384; }
    else if (b <= 3) { W = conv_W + (b - 1) * 16384; Wt = wt_all + b * 16384; NC = 128; tot = 16384; }
    else             { W = dec_W;                  Wt = wt_all + 4 * 16384; NC = 64;  tot = 8192; }
    for (int idx = t; idx < tot; idx += 256) {
        int n = idx >> 7, k = idx & 127;
        Wt[idx] = (_Float16)W[k * NC + n];
    }
}

// ---------------- CSR build (round-6 structure, verbatim) ----------------
__global__ __launch_bounds__(1024) void passA_hist(const int* __restrict__ dst,
                                                   int* __restrict__ counts,
                                                   int* __restrict__ total)
{
    __shared__ int hist[NNODES];
    const int b = blockIdx.x, t = threadIdx.x;
    for (int i = t; i < NNODES; i += 1024) hist[i] = 0;
    __syncthreads();
    const int e0 = b * CHUNK, e1 = e0 + CHUNK;
    for (int e = e0 + t; e < e1; e += 1024) atomicAdd(&hist[dst[e]], 1);
    __syncthreads();
    for (int i = t; i < NNODES; i += 1024) {
        int c = hist[i];
        counts[b * NNODES + i] = c;
        if (c) atomicAdd(&total[i], c);
    }
}

__global__ __launch_bounds__(1024) void scan_kernel(const int* __restrict__ total,
                                                    int* __restrict__ rs)
{
    __shared__ int part[1024];
    const int t = threadIdx.x;
    const int per = (NNODES + 1023) / 1024;
    const int begin = t * per;
    int s = 0;
    for (int j = 0; j < per; ++j) {
        int i = begin + j;
        if (i < NNODES) s += total[i];
    }
    part[t] = s;
    __syncthreads();
    for (int off = 1; off < 1024; off <<= 1) {
        int v = (t >= off) ? part[t - off] : 0;
        __syncthreads();
        part[t] += v;
        __syncthreads();
    }
    int excl = part[t] - s;
    for (int j = 0; j < per; ++j) {
        int i = begin + j;
        if (i < NNODES) {
            rs[i] = excl;
            excl += total[i];
        }
    }
    if (t == 1023) rs[NNODES] = part[1023];
}

__global__ __launch_bounds__(256) void mkbase_kernel(int* __restrict__ counts,
                                                     const int* __restrict__ rs)
{
    int i = blockIdx.x * blockDim.x + threadIdx.x;
    if (i >= NNODES) return;
    int run = rs[i];
    for (int b = 0; b < NB; ++b) {
        int c = counts[b * NNODES + i];
        counts[b * NNODES + i] = run;
        run += c;
    }
}

__global__ __launch_bounds__(1024) void passB_scatter(const int* __restrict__ src,
                                                      const int* __restrict__ dst,
                                                      const float* __restrict__ ew,
                                                      const int* __restrict__ base,
                                                      unsigned int* __restrict__ csr)
{
    __shared__ int cur[NNODES];
    const int b = blockIdx.x, t = threadIdx.x;
    for (int i = t; i < NNODES; i += 1024) cur[i] = base[b * NNODES + i];
    __syncthreads();
    const int e0 = b * CHUNK, e1 = e0 + CHUNK;
    for (int e = e0 + t; e < e1; e += 1024) {
        int d = dst[e];
        int p = atomicAdd(&cur[d], 1);
        unsigned int pk = (unsigned int)src[e]
                        | ((unsigned int)__half_as_ushort(__float2half_rn(ew[e])) << 16);
        csr[p] = pk;
    }
}

// ---------------- standalone MFMA GEMM (encoder / decoder) ----------------
template<int NCOLS, bool BIAS, bool TANH, bool OUTF32, bool AF32>
__global__ __launch_bounds__(256) void gemm_mfma(
    const void* __restrict__ Av,       // [M,128] fp32 or fp16 row-major
    const _Float16* __restrict__ Wt,   // [NCOLS,128] fp16 (n-major)
    const float* __restrict__ bias,    // [NCOLS] fp32
    void* __restrict__ outv,           // [M,NCOLS] fp16 or fp32
    int M)
{
    constexpr int TPW = NCOLS / 64;
    const int wave = __builtin_amdgcn_readfirstlane(threadIdx.x >> 6);
    const int lane = threadIdx.x & 63;
    const int base = blockIdx.x * 16;
    const int m  = lane & 15;
    const int kg = lane >> 4;
    const int row = base + m;

    f32x4 acc[TPW];
    #pragma unroll
    for (int t = 0; t < TPW; ++t) acc[t] = (f32x4){0.f, 0.f, 0.f, 0.f};

    #pragma unroll
    for (int ks = 0; ks < 4; ++ks) {
        half8 a;
        if (AF32) {
            const float* ap = (const float*)Av + (size_t)row * 128 + kg * 8 + ks * 32;
            float4 u0 = *(const float4*)(ap);
            float4 u1 = *(const float4*)(ap + 4);
            a[0] = (_Float16)u0.x; a[1] = (_Float16)u0.y;
            a[2] = (_Float16)u0.z; a[3] = (_Float16)u0.w;
            a[4] = (_Float16)u1.x; a[5] = (_Float16)u1.y;
            a[6] = (_Float16)u1.z; a[7] = (_Float16)u1.w;
        } else {
            a = *(const half8*)((const _Float16*)Av + (size_t)row * 128 + kg * 8 + ks * 32);
        }
        #pragma unroll
        for (int t = 0; t < TPW; ++t) {
            const int nt = wave + t * 4;
            half8 b = *(const half8*)(Wt + (size_t)(nt * 16 + m) * 128 + ks * 32 + kg * 8);
            acc[t] = __builtin_amdgcn_mfma_f32_16x16x32_f16(a, b, acc[t], 0, 0, 0);
        }
    }

    #pragma unroll
    for (int t = 0; t < TPW; ++t) {
        const int nt  = wave + t * 4;
        const int col = nt * 16 + m;
        float bv = BIAS ? bias[col] : 0.f;
        #pragma unroll
        for (int r = 0; r < 4; ++r) {
            int orow = base + kg * 4 + r;
            float v = acc[t][r] + bv;
            if (TANH) v = tanhf(v);
            if (OUTF32) ((float*)outv)[(size_t)orow * NCOLS + col] = v;
            else        ((_Float16*)outv)[(size_t)orow * NCOLS + col] = (_Float16)v;
        }
    }
}

// ---------------- fused conv layer: aggregate h -> LDS tile -> MFMA -> tanh ----------------
#define AGG_ACC(pw, vw)                                                  \
    do {                                                                 \
        __half wh; *(unsigned short*)&wh = (unsigned short)((pw) >> 16); \
        float w  = __half2float(wh);                                     \
        float2 f = __half22float2(*(const __half2*)&(vw));               \
        ax += w * f.x;                                                   \
        ay += w * f.y;                                                   \
    } while (0)

__global__ __launch_bounds__(512) void conv_fused(
    const unsigned int* __restrict__ hin,  // [N][64] fp16x2 rows
    const int* __restrict__ rs,            // [N+1]
    const unsigned int* __restrict__ csr,  // [E] packed (src | f16w<<16)
    const _Float16* __restrict__ Wt,       // [128,128] fp16 n-major
    const float* __restrict__ bias,        // [128] fp32
    _Float16* __restrict__ hout)           // [N,128] fp16
{
    __shared__ _Float16 Alds[16][136];     // +8 pad: b128 reads 2-way max

    const int t    = threadIdx.x;
    const int wv   = __builtin_amdgcn_readfirstlane(t >> 6);   // 0..7
    const int lane = t & 63;
    const int base = blockIdx.x * 16;      // N=10000 = 625*16 exact

    // each wave aggregates 2 nodes (rows wv*2, wv*2+1 of the tile)
    #pragma unroll
    for (int i = 0; i < 2; ++i) {
        const int r   = wv * 2 + i;
        const int wid = base + r;
        const int e0 = rs[wid];
        const int e1 = rs[wid + 1];

        float ax = 0.f, ay = 0.f;
        int e = e0;
        for (; e + 16 <= e1; e += 16) {
            unsigned int p[16], v[16];
            #pragma unroll
            for (int j = 0; j < 16; ++j) p[j] = csr[e + j];      // uniform -> s_load
            #pragma unroll
            for (int j = 0; j < 16; ++j) v[j] = hin[((p[j] & 0x3FFFu) << 6) + lane];
            #pragma unroll
            for (int j = 0; j < 16; ++j) AGG_ACC(p[j], v[j]);
        }
        for (; e + 4 <= e1; e += 4) {
            unsigned int p[4], v[4];
            #pragma unroll
            for (int j = 0; j < 4; ++j) p[j] = csr[e + j];
            #pragma unroll
            for (int j = 0; j < 4; ++j) v[j] = hin[((p[j] & 0x3FFFu) << 6) + lane];
            #pragma unroll
            for (int j = 0; j < 4; ++j) AGG_ACC(p[j], v[j]);
        }
        for (; e < e1; ++e) {
            unsigned int p = csr[e];
            unsigned int u = hin[((p & 0x3FFFu) << 6) + lane];
            AGG_ACC(p, u);
        }

        // store agg row (no bias/tanh here — they apply after the GEMM)
        _Float16 h2[2] = {(_Float16)ax, (_Float16)ay};
        *(unsigned int*)(&Alds[r][lane * 2]) = *(unsigned int*)h2;
    }
    __syncthreads();

    // MFMA: wave wv computes output cols wv*16 + m for all 16 rows
    const int m  = lane & 15;
    const int kg = lane >> 4;
    f32x4 acc = (f32x4){0.f, 0.f, 0.f, 0.f};
    #pragma unroll
    for (int ks = 0; ks < 4; ++ks) {
        half8 a  = *(const half8*)(&Alds[m][kg * 8 + ks * 32]);
        half8 bb = *(const half8*)(Wt + (size_t)(wv * 16 + m) * 128 + ks * 32 + kg * 8);
        acc = __builtin_amdgcn_mfma_f32_16x16x32_f16(a, bb, acc, 0, 0, 0);
    }

    const int col = wv * 16 + m;
    const float bv = bias[col];
    #pragma unroll
    for (int r = 0; r < 4; ++r) {
        int orow = base + kg * 4 + r;
        hout[(size_t)orow * 128 + col] = (_Float16)tanhf(acc[r] + bv);
    }
}

// ---------------- launch ----------------
extern "C" void kernel_launch(void* const* d_in, const int* in_sizes, int n_in,
                              void* d_out, int out_size, void* d_ws, size_t ws_size,
                              hipStream_t stream)
{
    const float* x      = (const float*)d_in[0];
    const int*   ei     = (const int*)  d_in[1];
    const float* ew     = (const float*)d_in[2];
    const float* enc_W  = (const float*)d_in[3];
    const float* enc_b  = (const float*)d_in[4];
    const float* conv_W = (const float*)d_in[5];
    const float* conv_b = (const float*)d_in[6];
    const float* dec_W  = (const float*)d_in[7];
    const float* dec_b  = (const float*)d_in[8];
    float* out = (float*)d_out;

    const int N = NNODES, E = NEDGES, H = HDIM;

    // workspace layout
    _Float16*     h      = (_Float16*)d_ws;                     // [N,128]  2.56MB
    _Float16*     h2     = h + (size_t)N * H;                   // [N,128]  2.56MB
    _Float16*     wt_all = h2 + (size_t)N * H;                  // 81920    160KB
    unsigned int* csr    = (unsigned int*)(wt_all + 5 * 16384); // [E]      2.56MB
    int*          counts = (int*)(csr + E);                     // [NB][N]  8MB
    int*          total  = counts + (size_t)NB * N;             // [N]
    int*          rs     = total + N;                           // [N+1]

    const int* src = ei;
    const int* dst = ei + E;

    prep_kernel<<<6, 256, 0, stream>>>(enc_W, conv_W, dec_W, wt_all, total);

    // encoder: h = tanh(x @ enc_W + enc_b)
    gemm_mfma<128, true, true, false, true><<<N / 16, 256, 0, stream>>>(x, wt_all, enc_b, h, N);

    passA_hist   <<<NB, 1024, 0, stream>>>(dst, counts, total);
    scan_kernel  <<<1, 1024, 0, stream>>>(total, rs);
    mkbase_kernel<<<(N + 255) / 256, 256, 0, stream>>>(counts, rs);
    passB_scatter<<<NB, 1024, 0, stream>>>(src, dst, ew, counts, csr);

    // conv layers: h_{l+1} = tanh((sum w*h_l[src]) @ W_l + b_l), ping-pong h/h2
    _Float16* cin  = h;
    _Float16* cout = h2;
    for (int i = 0; i < NLAYER; ++i) {
        conv_fused<<<N / 16, 512, 0, stream>>>((const unsigned int*)cin, rs, csr,
                                               wt_all + (1 + i) * 16384,
                                               conv_b + (size_t)i * H, cout);
        _Float16* tmp = cin; cin = cout; cout = tmp;
    }

    // decoder: out = cin @ dec_W + dec_b (fp32 out)
    gemm_mfma<64, true, false, true, false><<<N / 16, 256, 0, stream>>>(cin, wt_all + 4 * 16384, dec_b, out, N);
}

// Round 11
// 123.616 us; speedup vs baseline: 3.4403x; 1.0832x over previous
//
#include <hip/hip_runtime.h>
#include <hip/hip_bf16.h>
#include <hip/hip_fp16.h>

// GCN round 11: edge-parallel gather (4 edges / dwordx4 instruction, 16 lanes
// per row), shfl-broadcast CSR entries, shfl_xor group reduce. Decoder fused
// into conv layer 3. CSR build = round-6 structure. 9 launches.

#define NNODES 10000
#define NEDGES 640000
#define HDIM   128
#define CDIM   64
#define NLAYER 3
#define NB     200
#define CHUNK  (NEDGES / NB)

typedef _Float16 half8 __attribute__((ext_vector_type(8)));
typedef float    f32x4 __attribute__((ext_vector_type(4)));

// ---------------- prep: weights -> transposed fp16 [n][k]; zero total ----------------
__global__ __launch_bounds__(256) void prep_kernel(
    const float* __restrict__ enc_W,
    const float* __restrict__ conv_W,
    const float* __restrict__ dec_W,
    _Float16* __restrict__ wt_all,     // enc[16384] conv[3*16384] dec[8192]
    int* __restrict__ total)
{
    const int b = blockIdx.x, t = threadIdx.x;
    if (b == 5) {
        for (int i = t; i < NNODES; i += 256) total[i] = 0;
        return;
    }
    const float* W; _Float16* Wt; int NC, tot;
    if (b == 0)      { W = enc_W;                  Wt = wt_all;             NC = 128; tot = 16384; }
    else if (b <= 3) { W = conv_W + (b - 1) * 16384; Wt = wt_all + b * 16384; NC = 128; tot = 16384; }
    else             { W = dec_W;                  Wt = wt_all + 4 * 16384; NC = 64;  tot = 8192; }
    for (int idx = t; idx < tot; idx += 256) {
        int n = idx >> 7, k = idx & 127;
        Wt[idx] = (_Float16)W[k * NC + n];
    }
}

// ---------------- CSR build (round-6 structure, verbatim) ----------------
__global__ __launch_bounds__(1024) void passA_hist(const int* __restrict__ dst,
                                                   int* __restrict__ counts,
                                                   int* __restrict__ total)
{
    __shared__ int hist[NNODES];
    const int b = blockIdx.x, t = threadIdx.x;
    for (int i = t; i < NNODES; i += 1024) hist[i] = 0;
    __syncthreads();
    const int e0 = b * CHUNK, e1 = e0 + CHUNK;
    for (int e = e0 + t; e < e1; e += 1024) atomicAdd(&hist[dst[e]], 1);
    __syncthreads();
    for (int i = t; i < NNODES; i += 1024) {
        int c = hist[i];
        counts[b * NNODES + i] = c;
        if (c) atomicAdd(&total[i], c);
    }
}

__global__ __launch_bounds__(1024) void scan_kernel(const int* __restrict__ total,
                                                    int* __restrict__ rs)
{
    __shared__ int part[1024];
    const int t = threadIdx.x;
    const int per = (NNODES + 1023) / 1024;
    const int begin = t * per;
    int s = 0;
    for (int j = 0; j < per; ++j) {
        int i = begin + j;
        if (i < NNODES) s += total[i];
    }
    part[t] = s;
    __syncthreads();
    for (int off = 1; off < 1024; off <<= 1) {
        int v = (t >= off) ? part[t - off] : 0;
        __syncthreads();
        part[t] += v;
        __syncthreads();
    }
    int excl = part[t] - s;
    for (int j = 0; j < per; ++j) {
        int i = begin + j;
        if (i < NNODES) {
            rs[i] = excl;
            excl += total[i];
        }
    }
    if (t == 1023) rs[NNODES] = part[1023];
}

__global__ __launch_bounds__(256) void mkbase_kernel(int* __restrict__ counts,
                                                     const int* __restrict__ rs)
{
    int i = blockIdx.x * blockDim.x + threadIdx.x;
    if (i >= NNODES) return;
    int run = rs[i];
    for (int b = 0; b < NB; ++b) {
        int c = counts[b * NNODES + i];
        counts[b * NNODES + i] = run;
        run += c;
    }
}

__global__ __launch_bounds__(1024) void passB_scatter(const int* __restrict__ src,
                                                      const int* __restrict__ dst,
                                                      const float* __restrict__ ew,
                                                      const int* __restrict__ base,
                                                      unsigned int* __restrict__ csr)
{
    __shared__ int cur[NNODES];
    const int b = blockIdx.x, t = threadIdx.x;
    for (int i = t; i < NNODES; i += 1024) cur[i] = base[b * NNODES + i];
    __syncthreads();
    const int e0 = b * CHUNK, e1 = e0 + CHUNK;
    for (int e = e0 + t; e < e1; e += 1024) {
        int d = dst[e];
        int p = atomicAdd(&cur[d], 1);
        unsigned int pk = (unsigned int)src[e]
                        | ((unsigned int)__half_as_ushort(__float2half_rn(ew[e])) << 16);
        csr[p] = pk;
    }
}

// ---------------- encoder MFMA GEMM (fp32 A converted in-register) ----------------
__global__ __launch_bounds__(256) void gemm_enc(
    const float* __restrict__ A,       // [M,128] fp32
    const _Float16* __restrict__ Wt,   // [128,128] fp16 n-major
    const float* __restrict__ bias,    // [128]
    _Float16* __restrict__ outv,       // [M,128] fp16
    int M)
{
    const int wave = __builtin_amdgcn_readfirstlane(threadIdx.x >> 6);
    const int lane = threadIdx.x & 63;
    const int base = blockIdx.x * 16;
    const int m  = lane & 15;
    const int kg = lane >> 4;
    const int row = base + m;

    f32x4 acc[2];
    acc[0] = (f32x4){0.f, 0.f, 0.f, 0.f};
    acc[1] = (f32x4){0.f, 0.f, 0.f, 0.f};

    #pragma unroll
    for (int ks = 0; ks < 4; ++ks) {
        half8 a;
        const float* ap = A + (size_t)row * 128 + kg * 8 + ks * 32;
        float4 u0 = *(const float4*)(ap);
        float4 u1 = *(const float4*)(ap + 4);
        a[0] = (_Float16)u0.x; a[1] = (_Float16)u0.y;
        a[2] = (_Float16)u0.z; a[3] = (_Float16)u0.w;
        a[4] = (_Float16)u1.x; a[5] = (_Float16)u1.y;
        a[6] = (_Float16)u1.z; a[7] = (_Float16)u1.w;
        #pragma unroll
        for (int q = 0; q < 2; ++q) {
            const int nt = wave + q * 4;
            half8 b = *(const half8*)(Wt + (size_t)(nt * 16 + m) * 128 + ks * 32 + kg * 8);
            acc[q] = __builtin_amdgcn_mfma_f32_16x16x32_f16(a, b, acc[q], 0, 0, 0);
        }
    }

    #pragma unroll
    for (int q = 0; q < 2; ++q) {
        const int col = (wave + q * 4) * 16 + m;
        float bv = bias[col];
        #pragma unroll
        for (int r = 0; r < 4; ++r) {
            int orow = base + kg * 4 + r;
            outv[(size_t)orow * 128 + col] = (_Float16)tanhf(acc[q][r] + bv);
        }
    }
}

// ---------------- fused conv layer: edge-parallel aggregate -> MFMA -> tanh (-> dec) ----------------
template<bool DEC>
__global__ __launch_bounds__(512) void conv_fused(
    const unsigned char* __restrict__ hinB,  // [N][256] bytes (fp16 rows)
    const int* __restrict__ rs,              // [N+1]
    const unsigned int* __restrict__ csr,    // [E] packed (src | f16w<<16)
    const _Float16* __restrict__ Wt,         // [128,128] fp16 n-major
    const float* __restrict__ bias,          // [128] fp32
    _Float16* __restrict__ hout,             // [N,128] fp16 (unused if DEC)
    const _Float16* __restrict__ decWt,      // [64,128] fp16 n-major (DEC only)
    const float* __restrict__ dec_b,         // [64] (DEC only)
    float* __restrict__ decout)              // [N,64] fp32 (DEC only)
{
    __shared__ _Float16 Alds[16][136];

    const int t    = threadIdx.x;
    const int wv   = __builtin_amdgcn_readfirstlane(t >> 6);   // 0..7
    const int lane = t & 63;
    const int grp  = lane >> 4;    // 0..3: which edge of a 4-group
    const int li   = lane & 15;    // 16B-chunk index within a row
    const int base = blockIdx.x * 16;

    #pragma unroll
    for (int i = 0; i < 2; ++i) {
        const int r   = wv * 2 + i;
        const int wid = base + r;
        const int e0  = rs[wid];
        const int e1  = rs[wid + 1];

        float acc[8];
        #pragma unroll
        for (int q = 0; q < 8; ++q) acc[q] = 0.f;

        for (int sb = e0; sb < e1; sb += 64) {
            const int nrem = min(64, e1 - sb);
            // one vector load covers up to 64 edges of this node
            unsigned int vp = csr[sb + (lane < nrem ? lane : 0)];
            const int nfg = nrem >> 2;          // full 4-edge groups
            int g = 0;
            // 4 groups (16 edges) per iteration: 4 dwordx4 gathers in flight
            for (; g + 4 <= nfg; g += 4) {
                unsigned int ps[4]; uint4 v[4];
                #pragma unroll
                for (int q = 0; q < 4; ++q) ps[q] = __shfl(vp, 4 * (g + q) + grp, 64);
                #pragma unroll
                for (int q = 0; q < 4; ++q)
                    v[q] = *(const uint4*)(hinB + ((ps[q] & 0x3FFFu) << 8) + (li << 4));
                #pragma unroll
                for (int q = 0; q < 4; ++q) {
                    __half wh; *(unsigned short*)&wh = (unsigned short)(ps[q] >> 16);
                    float w = __half2float(wh);
                    float2 f0 = __half22float2(*(const __half2*)&v[q].x);
                    float2 f1 = __half22float2(*(const __half2*)&v[q].y);
                    float2 f2 = __half22float2(*(const __half2*)&v[q].z);
                    float2 f3 = __half22float2(*(const __half2*)&v[q].w);
                    acc[0] += w * f0.x; acc[1] += w * f0.y;
                    acc[2] += w * f1.x; acc[3] += w * f1.y;
                    acc[4] += w * f2.x; acc[5] += w * f2.y;
                    acc[6] += w * f3.x; acc[7] += w * f3.y;
                }
            }
            // leftover full groups
            for (; g < nfg; ++g) {
                unsigned int ps = __shfl(vp, 4 * g + grp, 64);
                uint4 v = *(const uint4*)(hinB + ((ps & 0x3FFFu) << 8) + (li << 4));
                __half wh; *(unsigned short*)&wh = (unsigned short)(ps >> 16);
                float w = __half2float(wh);
                float2 f0 = __half22float2(*(const __half2*)&v.x);
                float2 f1 = __half22float2(*(const __half2*)&v.y);
                float2 f2 = __half22float2(*(const __half2*)&v.z);
                float2 f3 = __half22float2(*(const __half2*)&v.w);
                acc[0] += w * f0.x; acc[1] += w * f0.y;
                acc[2] += w * f1.x; acc[3] += w * f1.y;
                acc[4] += w * f2.x; acc[5] += w * f2.y;
                acc[6] += w * f3.x; acc[7] += w * f3.y;
            }
            // tail group (1..3 valid edges): mask weight bits to +0 for invalid
            if (nrem & 3) {
                unsigned int ps = __shfl(vp, 4 * g + grp, 64);
                if (4 * g + grp >= nrem) ps &= 0x3FFFu;   // weight := +0.0, src stays valid
                uint4 v = *(const uint4*)(hinB + ((ps & 0x3FFFu) << 8) + (li << 4));
                __half wh; *(unsigned short*)&wh = (unsigned short)(ps >> 16);
                float w = __half2float(wh);
                float2 f0 = __half22float2(*(const __half2*)&v.x);
                float2 f1 = __half22float2(*(const __half2*)&v.y);
                float2 f2 = __half22float2(*(const __half2*)&v.z);
                float2 f3 = __half22float2(*(const __half2*)&v.w);
                acc[0] += w * f0.x; acc[1] += w * f0.y;
                acc[2] += w * f1.x; acc[3] += w * f1.y;
                acc[4] += w * f2.x; acc[5] += w * f2.y;
                acc[6] += w * f3.x; acc[7] += w * f3.y;
            }
        }

        // fold the 4 lane-groups: each lane-group holds a disjoint edge subset
        #pragma unroll
        for (int q = 0; q < 8; ++q) {
            float s = acc[q];
            s += __shfl_xor(s, 16, 64);
            s += __shfl_xor(s, 32, 64);
            acc[q] = s;
        }

        if (grp == 0) {
            _Float16 hv[8];
            #pragma unroll
            for (int q = 0; q < 8; ++q) hv[q] = (_Float16)acc[q];
            *(uint4*)(&Alds[r][li * 8]) = *(uint4*)hv;
        }
    }
    __syncthreads();

    // MFMA: wave wv computes cols wv*16 + m for all 16 rows
    const int m  = li;
    const int kg = grp;
    f32x4 macc = (f32x4){0.f, 0.f, 0.f, 0.f};
    #pragma unroll
    for (int ks = 0; ks < 4; ++ks) {
        half8 a  = *(const half8*)(&Alds[m][kg * 8 + ks * 32]);
        half8 bb = *(const half8*)(Wt + (size_t)(wv * 16 + m) * 128 + ks * 32 + kg * 8);
        macc = __builtin_amdgcn_mfma_f32_16x16x32_f16(a, bb, macc, 0, 0, 0);
    }

    const int col = wv * 16 + m;
    const float bv = bias[col];
    float tv[4];
    #pragma unroll
    for (int r = 0; r < 4; ++r) tv[r] = tanhf(macc[r] + bv);

    if (!DEC) {
        #pragma unroll
        for (int r = 0; r < 4; ++r)
            hout[(size_t)(base + kg * 4 + r) * 128 + col] = (_Float16)tv[r];
    } else {
        __syncthreads();   // Alds reads complete; reuse tile for tanh'd h
        #pragma unroll
        for (int r = 0; r < 4; ++r) Alds[kg * 4 + r][col] = (_Float16)tv[r];
        __syncthreads();
        if (wv < 4) {
            f32x4 dacc = (f32x4){0.f, 0.f, 0.f, 0.f};
            #pragma unroll
            for (int ks = 0; ks < 4; ++ks) {
                half8 a  = *(const half8*)(&Alds[m][kg * 8 + ks * 32]);
                half8 bb = *(const half8*)(decWt + (size_t)(wv * 16 + m) * 128 + ks * 32 + kg * 8);
                dacc = __builtin_amdgcn_mfma_f32_16x16x32_f16(a, bb, dacc, 0, 0, 0);
            }
            const float dbv = dec_b[wv * 16 + m];
            #pragma unroll
            for (int r = 0; r < 4; ++r)
                decout[(size_t)(base + kg * 4 + r) * 64 + wv * 16 + m] = dacc[r] + dbv;
        }
    }
}

// ---------------- launch ----------------
extern "C" void kernel_launch(void* const* d_in, const int* in_sizes, int n_in,
                              void* d_out, int out_size, void* d_ws, size_t ws_size,
                              hipStream_t stream)
{
    const float* x      = (const float*)d_in[0];
    const int*   ei     = (const int*)  d_in[1];
    const float* ew     = (const float*)d_in[2];
    const float* enc_W  = (const float*)d_in[3];
    const float* enc_b  = (const float*)d_in[4];
    const float* conv_W = (const float*)d_in[5];
    const float* conv_b = (const float*)d_in[6];
    const float* dec_W  = (const float*)d_in[7];
    const float* dec_b  = (const float*)d_in[8];
    float* out = (float*)d_out;

    const int N = NNODES, E = NEDGES, H = HDIM;

    // workspace layout
    _Float16*     h      = (_Float16*)d_ws;                     // [N,128]  2.56MB
    _Float16*     h2     = h + (size_t)N * H;                   // [N,128]  2.56MB
    _Float16*     wt_all = h2 + (size_t)N * H;                  // 81920    160KB
    unsigned int* csr    = (unsigned int*)(wt_all + 5 * 16384); // [E]      2.56MB
    int*          counts = (int*)(csr + E);                     // [NB][N]  8MB
    int*          total  = counts + (size_t)NB * N;             // [N]
    int*          rs     = total + N;                           // [N+1]

    const int* src = ei;
    const int* dst = ei + E;

    prep_kernel<<<6, 256, 0, stream>>>(enc_W, conv_W, dec_W, wt_all, total);

    // encoder: h = tanh(x @ enc_W + enc_b)
    gemm_enc<<<N / 16, 256, 0, stream>>>(x, wt_all, enc_b, h, N);

    passA_hist   <<<NB, 1024, 0, stream>>>(dst, counts, total);
    scan_kernel  <<<1, 1024, 0, stream>>>(total, rs);
    mkbase_kernel<<<(N + 255) / 256, 256, 0, stream>>>(counts, rs);
    passB_scatter<<<NB, 1024, 0, stream>>>(src, dst, ew, counts, csr);

    // conv layers (linearity reorder): h_{l+1} = tanh((sum w*h_l[src]) @ W_l + b_l)
    conv_fused<false><<<N / 16, 512, 0, stream>>>((const unsigned char*)h, rs, csr,
                                                  wt_all + 1 * 16384, conv_b + 0 * H,
                                                  h2, nullptr, nullptr, nullptr);
    conv_fused<false><<<N / 16, 512, 0, stream>>>((const unsigned char*)h2, rs, csr,
                                                  wt_all + 2 * 16384, conv_b + 1 * H,
                                                  h, nullptr, nullptr, nullptr);
    // layer 3 + decoder fused
    conv_fused<true><<<N / 16, 512, 0, stream>>>((const unsigned char*)h, rs, csr,
                                                 wt_all + 3 * 16384, conv_b + 2 * H,
                                                 h2, wt_all + 4 * 16384, dec_b, out);
}

// Round 12
// 120.565 us; speedup vs baseline: 3.5273x; 1.0253x over previous
//
#include <hip/hip_runtime.h>
#include <hip/hip_bf16.h>
#include <hip/hip_fp16.h>

// GCN round 12: conv aggregate accumulates via v_fma_mix (fp16 operand, fp32
// accum — no explicit cvt); encoder GEMM fused into passA (block-role split).
// 8 launches: prep, enc+hist, scan, mkbase, passB, conv1, conv2, conv3+dec.

#define NNODES 10000
#define NEDGES 640000
#define HDIM   128
#define CDIM   64
#define NLAYER 3
#define NB     200
#define CHUNK  (NEDGES / NB)
#define ENCB   157               // encoder blocks in fused kernel (157*4 >= 625 tiles)

typedef _Float16 half8 __attribute__((ext_vector_type(8)));
typedef float    f32x4 __attribute__((ext_vector_type(4)));

// ---------------- prep: weights -> transposed fp16 [n][k]; zero total ----------------
__global__ __launch_bounds__(256) void prep_kernel(
    const float* __restrict__ enc_W,
    const float* __restrict__ conv_W,
    const float* __restrict__ dec_W,
    _Float16* __restrict__ wt_all,     // enc[16384] conv[3*16384] dec[8192]
    int* __restrict__ total)
{
    const int b = blockIdx.x, t = threadIdx.x;
    if (b == 5) {
        for (int i = t; i < NNODES; i += 256) total[i] = 0;
        return;
    }
    const float* W; _Float16* Wt; int NC, tot;
    if (b == 0)      { W = enc_W;                  Wt = wt_all;             NC = 128; tot = 16384; }
    else if (b <= 3) { W = conv_W + (b - 1) * 16384; Wt = wt_all + b * 16384; NC = 128; tot = 16384; }
    else             { W = dec_W;                  Wt = wt_all + 4 * 16384; NC = 64;  tot = 8192; }
    for (int idx = t; idx < tot; idx += 256) {
        int n = idx >> 7, k = idx & 127;
        Wt[idx] = (_Float16)W[k * NC + n];
    }
}

// ---- encoder tile (16 rows), executed by a 256-thread subgroup ----
__device__ __forceinline__ void enc_tile(int tile, int tid,
    const float* __restrict__ A, const _Float16* __restrict__ Wt,
    const float* __restrict__ bias, _Float16* __restrict__ outv)
{
    const int wave = tid >> 6;
    const int lane = tid & 63;
    const int base = tile * 16;
    const int m  = lane & 15;
    const int kg = lane >> 4;
    const int row = base + m;

    f32x4 acc[2];
    acc[0] = (f32x4){0.f, 0.f, 0.f, 0.f};
    acc[1] = (f32x4){0.f, 0.f, 0.f, 0.f};

    #pragma unroll
    for (int ks = 0; ks < 4; ++ks) {
        half8 a;
        const float* ap = A + (size_t)row * 128 + kg * 8 + ks * 32;
        float4 u0 = *(const float4*)(ap);
        float4 u1 = *(const float4*)(ap + 4);
        a[0] = (_Float16)u0.x; a[1] = (_Float16)u0.y;
        a[2] = (_Float16)u0.z; a[3] = (_Float16)u0.w;
        a[4] = (_Float16)u1.x; a[5] = (_Float16)u1.y;
        a[6] = (_Float16)u1.z; a[7] = (_Float16)u1.w;
        #pragma unroll
        for (int q = 0; q < 2; ++q) {
            const int nt = wave + q * 4;
            half8 b = *(const half8*)(Wt + (size_t)(nt * 16 + m) * 128 + ks * 32 + kg * 8);
            acc[q] = __builtin_amdgcn_mfma_f32_16x16x32_f16(a, b, acc[q], 0, 0, 0);
        }
    }

    #pragma unroll
    for (int q = 0; q < 2; ++q) {
        const int col = (wave + q * 4) * 16 + m;
        float bv = bias[col];
        #pragma unroll
        for (int r = 0; r < 4; ++r) {
            int orow = base + kg * 4 + r;
            outv[(size_t)orow * 128 + col] = (_Float16)tanhf(acc[q][r] + bv);
        }
    }
}

// ---------------- fused: hist (blocks 0..NB-1) + encoder (blocks NB..) ----------------
__global__ __launch_bounds__(1024) void enc_hist_kernel(
    const int* __restrict__ dst,
    int* __restrict__ counts,
    int* __restrict__ total,
    const float* __restrict__ x,
    const _Float16* __restrict__ encWt,
    const float* __restrict__ enc_b,
    _Float16* __restrict__ h)
{
    __shared__ int hist[NNODES];
    const int b = blockIdx.x, t = threadIdx.x;

    if (b >= NB) {
        int tile = (b - NB) * 4 + (t >> 8);
        if (tile < NNODES / 16)
            enc_tile(tile, t & 255, x, encWt, enc_b, h);
        return;
    }

    for (int i = t; i < NNODES; i += 1024) hist[i] = 0;
    __syncthreads();
    const int e0 = b * CHUNK, e1 = e0 + CHUNK;
    for (int e = e0 + t; e < e1; e += 1024) atomicAdd(&hist[dst[e]], 1);
    __syncthreads();
    for (int i = t; i < NNODES; i += 1024) {
        int c = hist[i];
        counts[b * NNODES + i] = c;
        if (c) atomicAdd(&total[i], c);
    }
}

// ---------------- scan / mkbase / passB (round-6 structure) ----------------
__global__ __launch_bounds__(1024) void scan_kernel(const int* __restrict__ total,
                                                    int* __restrict__ rs)
{
    __shared__ int part[1024];
    const int t = threadIdx.x;
    const int per = (NNODES + 1023) / 1024;
    const int begin = t * per;
    int s = 0;
    for (int j = 0; j < per; ++j) {
        int i = begin + j;
        if (i < NNODES) s += total[i];
    }
    part[t] = s;
    __syncthreads();
    for (int off = 1; off < 1024; off <<= 1) {
        int v = (t >= off) ? part[t - off] : 0;
        __syncthreads();
        part[t] += v;
        __syncthreads();
    }
    int excl = part[t] - s;
    for (int j = 0; j < per; ++j) {
        int i = begin + j;
        if (i < NNODES) {
            rs[i] = excl;
            excl += total[i];
        }
    }
    if (t == 1023) rs[NNODES] = part[1023];
}

__global__ __launch_bounds__(256) void mkbase_kernel(int* __restrict__ counts,
                                                     const int* __restrict__ rs)
{
    int i = blockIdx.x * blockDim.x + threadIdx.x;
    if (i >= NNODES) return;
    int run = rs[i];
    for (int b = 0; b < NB; ++b) {
        int c = counts[b * NNODES + i];
        counts[b * NNODES + i] = run;
        run += c;
    }
}

__global__ __launch_bounds__(1024) void passB_scatter(const int* __restrict__ src,
                                                      const int* __restrict__ dst,
                                                      const float* __restrict__ ew,
                                                      const int* __restrict__ base,
                                                      unsigned int* __restrict__ csr)
{
    __shared__ int cur[NNODES];
    const int b = blockIdx.x, t = threadIdx.x;
    for (int i = t; i < NNODES; i += 1024) cur[i] = base[b * NNODES + i];
    __syncthreads();
    const int e0 = b * CHUNK, e1 = e0 + CHUNK;
    for (int e = e0 + t; e < e1; e += 1024) {
        int d = dst[e];
        int p = atomicAdd(&cur[d], 1);
        unsigned int pk = (unsigned int)src[e]
                        | ((unsigned int)__half_as_ushort(__float2half_rn(ew[e])) << 16);
        csr[p] = pk;
    }
}

// ---------------- fused conv layer ----------------
// per-edge accumulate: fp16 operand x fp32 weight, fp32 accum -> v_fma_mix_f32
#define EDGE_ACC(pk, vv)                                                 \
    do {                                                                 \
        __half wh; *(unsigned short*)&wh = (unsigned short)((pk) >> 16); \
        float w = __half2float(wh);                                      \
        half8 hv = *(const half8*)&(vv);                                 \
        _Pragma("unroll")                                                \
        for (int j = 0; j < 8; ++j)                                      \
            acc[j] = fmaf((float)hv[j], w, acc[j]);                      \
    } while (0)

template<bool DEC>
__global__ __launch_bounds__(512) void conv_fused(
    const unsigned char* __restrict__ hinB,  // [N][256] bytes (fp16 rows)
    const int* __restrict__ rs,              // [N+1]
    const unsigned int* __restrict__ csr,    // [E] packed (src | f16w<<16)
    const _Float16* __restrict__ Wt,         // [128,128] fp16 n-major
    const float* __restrict__ bias,          // [128] fp32
    _Float16* __restrict__ hout,             // [N,128] fp16 (unused if DEC)
    const _Float16* __restrict__ decWt,      // [64,128] fp16 n-major (DEC only)
    const float* __restrict__ dec_b,         // [64] (DEC only)
    float* __restrict__ decout)              // [N,64] fp32 (DEC only)
{
    __shared__ _Float16 Alds[16][136];

    const int t    = threadIdx.x;
    const int wv   = __builtin_amdgcn_readfirstlane(t >> 6);   // 0..7
    const int lane = t & 63;
    const int grp  = lane >> 4;    // 0..3: which edge of a 4-group
    const int li   = lane & 15;    // 16B-chunk index within a row
    const int base = blockIdx.x * 16;

    #pragma unroll
    for (int i = 0; i < 2; ++i) {
        const int r   = wv * 2 + i;
        const int wid = base + r;
        const int e0  = rs[wid];
        const int e1  = rs[wid + 1];

        float acc[8];
        #pragma unroll
        for (int q = 0; q < 8; ++q) acc[q] = 0.f;

        for (int sb = e0; sb < e1; sb += 64) {
            const int nrem = min(64, e1 - sb);
            unsigned int vp = csr[sb + (lane < nrem ? lane : 0)];
            const int nfg = nrem >> 2;
            int g = 0;
            for (; g + 4 <= nfg; g += 4) {
                unsigned int ps[4]; uint4 v[4];
                #pragma unroll
                for (int q = 0; q < 4; ++q) ps[q] = __shfl(vp, 4 * (g + q) + grp, 64);
                #pragma unroll
                for (int q = 0; q < 4; ++q)
                    v[q] = *(const uint4*)(hinB + ((ps[q] & 0x3FFFu) << 8) + (li << 4));
                #pragma unroll
                for (int q = 0; q < 4; ++q) EDGE_ACC(ps[q], v[q]);
            }
            for (; g < nfg; ++g) {
                unsigned int ps = __shfl(vp, 4 * g + grp, 64);
                uint4 v = *(const uint4*)(hinB + ((ps & 0x3FFFu) << 8) + (li << 4));
                EDGE_ACC(ps, v);
            }
            if (nrem & 3) {
                unsigned int ps = __shfl(vp, 4 * g + grp, 64);
                if (4 * g + grp >= nrem) ps &= 0x3FFFu;   // weight := +0.0
                uint4 v = *(const uint4*)(hinB + ((ps & 0x3FFFu) << 8) + (li << 4));
                EDGE_ACC(ps, v);
            }
        }

        #pragma unroll
        for (int q = 0; q < 8; ++q) {
            float s = acc[q];
            s += __shfl_xor(s, 16, 64);
            s += __shfl_xor(s, 32, 64);
            acc[q] = s;
        }

        if (grp == 0) {
            _Float16 hv[8];
            #pragma unroll
            for (int q = 0; q < 8; ++q) hv[q] = (_Float16)acc[q];
            *(uint4*)(&Alds[r][li * 8]) = *(uint4*)hv;
        }
    }
    __syncthreads();

    const int m  = li;
    const int kg = grp;
    f32x4 macc = (f32x4){0.f, 0.f, 0.f, 0.f};
    #pragma unroll
    for (int ks = 0; ks < 4; ++ks) {
        half8 a  = *(const half8*)(&Alds[m][kg * 8 + ks * 32]);
        half8 bb = *(const half8*)(Wt + (size_t)(wv * 16 + m) * 128 + ks * 32 + kg * 8);
        macc = __builtin_amdgcn_mfma_f32_16x16x32_f16(a, bb, macc, 0, 0, 0);
    }

    const int col = wv * 16 + m;
    const float bv = bias[col];
    float tv[4];
    #pragma unroll
    for (int r = 0; r < 4; ++r) tv[r] = tanhf(macc[r] + bv);

    if (!DEC) {
        #pragma unroll
        for (int r = 0; r < 4; ++r)
            hout[(size_t)(base + kg * 4 + r) * 128 + col] = (_Float16)tv[r];
    } else {
        __syncthreads();
        #pragma unroll
        for (int r = 0; r < 4; ++r) Alds[kg * 4 + r][col] = (_Float16)tv[r];
        __syncthreads();
        if (wv < 4) {
            f32x4 dacc = (f32x4){0.f, 0.f, 0.f, 0.f};
            #pragma unroll
            for (int ks = 0; ks < 4; ++ks) {
                half8 a  = *(const half8*)(&Alds[m][kg * 8 + ks * 32]);
                half8 bb = *(const half8*)(decWt + (size_t)(wv * 16 + m) * 128 + ks * 32 + kg * 8);
                dacc = __builtin_amdgcn_mfma_f32_16x16x32_f16(a, bb, dacc, 0, 0, 0);
            }
            const float dbv = dec_b[wv * 16 + m];
            #pragma unroll
            for (int r = 0; r < 4; ++r)
                decout[(size_t)(base + kg * 4 + r) * 64 + wv * 16 + m] = dacc[r] + dbv;
        }
    }
}

// ---------------- launch ----------------
extern "C" void kernel_launch(void* const* d_in, const int* in_sizes, int n_in,
                              void* d_out, int out_size, void* d_ws, size_t ws_size,
                              hipStream_t stream)
{
    const float* x      = (const float*)d_in[0];
    const int*   ei     = (const int*)  d_in[1];
    const float* ew     = (const float*)d_in[2];
    const float* enc_W  = (const float*)d_in[3];
    const float* enc_b  = (const float*)d_in[4];
    const float* conv_W = (const float*)d_in[5];
    const float* conv_b = (const float*)d_in[6];
    const float* dec_W  = (const float*)d_in[7];
    const float* dec_b  = (const float*)d_in[8];
    float* out = (float*)d_out;

    const int N = NNODES, E = NEDGES, H = HDIM;

    // workspace layout
    _Float16*     h      = (_Float16*)d_ws;                     // [N,128]  2.56MB
    _Float16*     h2     = h + (size_t)N * H;                   // [N,128]  2.56MB
    _Float16*     wt_all = h2 + (size_t)N * H;                  // 81920    160KB
    unsigned int* csr    = (unsigned int*)(wt_all + 5 * 16384); // [E]      2.56MB
    int*          counts = (int*)(csr + E);                     // [NB][N]  8MB
    int*          total  = counts + (size_t)NB * N;             // [N]
    int*          rs     = total + N;                           // [N+1]

    const int* src = ei;
    const int* dst = ei + E;

    prep_kernel<<<6, 256, 0, stream>>>(enc_W, conv_W, dec_W, wt_all, total);

    // fused: hist (200 blocks) + encoder (157 blocks)
    enc_hist_kernel<<<NB + ENCB, 1024, 0, stream>>>(dst, counts, total, x, wt_all, enc_b, h);

    scan_kernel  <<<1, 1024, 0, stream>>>(total, rs);
    mkbase_kernel<<<(N + 255) / 256, 256, 0, stream>>>(counts, rs);
    passB_scatter<<<NB, 1024, 0, stream>>>(src, dst, ew, counts, csr);

    // conv layers (linearity reorder): h_{l+1} = tanh((sum w*h_l[src]) @ W_l + b_l)
    conv_fused<false><<<N / 16, 512, 0, stream>>>((const unsigned char*)h, rs, csr,
                                                  wt_all + 1 * 16384, conv_b + 0 * H,
                                                  h2, nullptr, nullptr, nullptr);
    conv_fused<false><<<N / 16, 512, 0, stream>>>((const unsigned char*)h2, rs, csr,
                                                  wt_all + 2 * 16384, conv_b + 1 * H,
                                                  h, nullptr, nullptr, nullptr);
    conv_fused<true><<<N / 16, 512, 0, stream>>>((const unsigned char*)h, rs, csr,
                                                 wt_all + 3 * 16384, conv_b + 2 * H,
                                                 h2, wt_all + 4 * 16384, dec_b, out);
}